// Round 1
// baseline (288.424 us; speedup 1.0000x reference)
//
#include <hip/hip_runtime.h>

#define NPIX 15000
#define IMG_H 200
#define IMG_W 75
#define NVEC 3750   // NPIX / 4

// Pre-kernel: wp[p] = lane_W[(p%200)*75 + p/200]  (the reshape/transpose permutation)
__global__ void eb_permute_w(const float* __restrict__ lane_W, float* __restrict__ wp) {
    int p = blockIdx.x * blockDim.x + threadIdx.x;
    if (p < NPIX) {
        int w = p / IMG_H;          // 0..74
        int h = p - w * IMG_H;      // 0..199
        wp[p] = lane_W[h * IMG_W + w];
    }
}

__global__ __launch_bounds__(256) void eb_fused(
    const float* __restrict__ rgb,       // [B, 15000]
    const float* __restrict__ distance,  // [B]
    const float* __restrict__ kmph,      // [B]
    const float* __restrict__ wp,        // [15000] permuted lane weights (d_ws)
    const float* __restrict__ lane_b,    // [1]
    const float* __restrict__ W1, const float* __restrict__ b1,   // [3,16],[16]
    const float* __restrict__ W2, const float* __restrict__ b2,   // [16,32],[32]
    const float* __restrict__ W3, const float* __restrict__ b3,   // [32,32],[32]
    const float* __restrict__ W4, const float* __restrict__ b4,   // [32,16],[16]
    const float* __restrict__ Wv, const float* __restrict__ bv,   // [16,1],[1]
    const float* __restrict__ Wa, const float* __restrict__ ba,   // [16,4],[4]
    float* __restrict__ out)             // [B, 4]
{
    const int b = blockIdx.x;
    const int t = threadIdx.x;

    // ---- coalesced float4 reduction over the row (rows are 16B aligned: 60000 % 16 == 0)
    const float4* __restrict__ row = reinterpret_cast<const float4*>(rgb + (size_t)b * NPIX);
    const float4* __restrict__ wv4 = reinterpret_cast<const float4*>(wp);

    float acc = 0.0f;
    for (int i = t; i < NVEC; i += 256) {
        float4 v = row[i];
        float4 w = wv4[i];
        acc += (v.x > 0.0f ? w.x : 0.0f);
        acc += (v.y > 0.0f ? w.y : 0.0f);
        acc += (v.z > 0.0f ? w.z : 0.0f);
        acc += (v.w > 0.0f ? w.w : 0.0f);
    }

    // ---- wave64 shuffle reduce, then cross-wave via LDS
    #pragma unroll
    for (int off = 32; off > 0; off >>= 1)
        acc += __shfl_down(acc, off, 64);

    __shared__ float partial[4];
    const int wave = t >> 6;
    if ((t & 63) == 0) partial[wave] = acc;
    __syncthreads();

    if (t == 0) {
        float steer = ((partial[0] + partial[1]) + (partial[2] + partial[3])) + lane_b[0];

        const float fc0 = steer;
        const float fc1 = distance[b];
        const float fc2 = kmph[b];

        // layer 1: 3 -> 16, relu
        float h1[16];
        #pragma unroll
        for (int j = 0; j < 16; ++j) {
            float s = b1[j];
            s += fc0 * W1[0 * 16 + j];
            s += fc1 * W1[1 * 16 + j];
            s += fc2 * W1[2 * 16 + j];
            h1[j] = s > 0.0f ? s : 0.0f;
        }
        // layer 2: 16 -> 32, relu
        float h2[32];
        #pragma unroll
        for (int j = 0; j < 32; ++j) {
            float s = b2[j];
            #pragma unroll
            for (int i = 0; i < 16; ++i) s += h1[i] * W2[i * 32 + j];
            h2[j] = s > 0.0f ? s : 0.0f;
        }
        // layer 3: 32 -> 32, relu
        float h3[32];
        #pragma unroll
        for (int j = 0; j < 32; ++j) {
            float s = b3[j];
            #pragma unroll
            for (int i = 0; i < 32; ++i) s += h2[i] * W3[i * 32 + j];
            h3[j] = s > 0.0f ? s : 0.0f;
        }
        // layer 4: 32 -> 16 (no relu)
        float h4[16];
        #pragma unroll
        for (int j = 0; j < 16; ++j) {
            float s = b4[j];
            #pragma unroll
            for (int i = 0; i < 32; ++i) s += h3[i] * W4[i * 16 + j];
            h4[j] = s;
        }
        // value head 16 -> 1
        float value = bv[0];
        #pragma unroll
        for (int i = 0; i < 16; ++i) value += h4[i] * Wv[i];
        // advantage head 16 -> 4
        float a0 = ba[0], a1 = ba[1], a2 = ba[2], a3 = ba[3];
        #pragma unroll
        for (int i = 0; i < 16; ++i) {
            a0 += h4[i] * Wa[i * 4 + 0];
            a1 += h4[i] * Wa[i * 4 + 1];
            a2 += h4[i] * Wa[i * 4 + 2];
            a3 += h4[i] * Wa[i * 4 + 3];
        }
        float mean = (((a0 + a1) + a2) + a3) * 0.25f;

        float* o = out + (size_t)b * 4;
        o[0] = value + (a0 - mean);
        o[1] = value + (a1 - mean);
        o[2] = value + (a2 - mean);
        o[3] = value + (a3 - mean);
    }
}

extern "C" void kernel_launch(void* const* d_in, const int* in_sizes, int n_in,
                              void* d_out, int out_size, void* d_ws, size_t ws_size,
                              hipStream_t stream) {
    const float* rgb      = (const float*)d_in[0];
    const float* distance = (const float*)d_in[1];
    const float* kmph     = (const float*)d_in[2];
    const float* lane_W   = (const float*)d_in[3];
    const float* lane_b   = (const float*)d_in[4];
    const float* W1 = (const float*)d_in[5];
    const float* b1 = (const float*)d_in[6];
    const float* W2 = (const float*)d_in[7];
    const float* b2 = (const float*)d_in[8];
    const float* W3 = (const float*)d_in[9];
    const float* b3 = (const float*)d_in[10];
    const float* W4 = (const float*)d_in[11];
    const float* b4 = (const float*)d_in[12];
    const float* Wv = (const float*)d_in[13];
    const float* bv = (const float*)d_in[14];
    const float* Wa = (const float*)d_in[15];
    const float* ba = (const float*)d_in[16];

    const int B = in_sizes[1];          // distance has B elements
    float* wp = (float*)d_ws;           // 15000 floats = 60 KB scratch

    eb_permute_w<<<(NPIX + 255) / 256, 256, 0, stream>>>(lane_W, wp);
    eb_fused<<<B, 256, 0, stream>>>(rgb, distance, kmph, wp, lane_b,
                                    W1, b1, W2, b2, W3, b3, W4, b4,
                                    Wv, bv, Wa, ba, (float*)d_out);
}

// Round 2
// 191.090 us; speedup vs baseline: 1.5094x; 1.5094x over previous
//
#include <hip/hip_runtime.h>

#define NPIX 15000
#define IMG_H 200
#define IMG_W 75
#define NVEC 3750   // NPIX / 4

// Pre-kernel: wp[p] = lane_W[(p%200)*75 + p/200]  (the reshape/transpose permutation)
__global__ void eb_permute_w(const float* __restrict__ lane_W, float* __restrict__ wp) {
    int p = blockIdx.x * blockDim.x + threadIdx.x;
    if (p < NPIX) {
        int w = p / IMG_H;          // 0..74
        int h = p - w * IMG_H;      // 0..199
        wp[p] = lane_W[h * IMG_W + w];
    }
}

// Phase 1: steer[b] = sum_p (rgb[b,p] > 0 ? wp[p] : 0) + lane_b   (pure streaming)
__global__ __launch_bounds__(256) void eb_reduce(
    const float* __restrict__ rgb,       // [B, 15000]
    const float* __restrict__ wp,        // [15000] permuted lane weights
    const float* __restrict__ lane_b,    // [1]
    float* __restrict__ steer)           // [B]
{
    const int b = blockIdx.x;
    const int t = threadIdx.x;

    const float4* __restrict__ row = reinterpret_cast<const float4*>(rgb + (size_t)b * NPIX);
    const float4* __restrict__ wv4 = reinterpret_cast<const float4*>(wp);

    float acc = 0.0f;
    for (int i = t; i < NVEC; i += 256) {
        float4 v = row[i];
        float4 w = wv4[i];
        acc += (v.x > 0.0f ? w.x : 0.0f);
        acc += (v.y > 0.0f ? w.y : 0.0f);
        acc += (v.z > 0.0f ? w.z : 0.0f);
        acc += (v.w > 0.0f ? w.w : 0.0f);
    }

    #pragma unroll
    for (int off = 32; off > 0; off >>= 1)
        acc += __shfl_down(acc, off, 64);

    __shared__ float partial[4];
    const int wave = t >> 6;
    if ((t & 63) == 0) partial[wave] = acc;
    __syncthreads();

    if (t == 0)
        steer[b] = ((partial[0] + partial[1]) + (partial[2] + partial[3])) + lane_b[0];
}

// Phase 2: one thread per batch element runs the whole dueling MLP.
__global__ __launch_bounds__(256) void eb_mlp(
    const float* __restrict__ steer,     // [B]
    const float* __restrict__ distance,  // [B]
    const float* __restrict__ kmph,      // [B]
    const float* __restrict__ W1, const float* __restrict__ b1,   // [3,16],[16]
    const float* __restrict__ W2, const float* __restrict__ b2,   // [16,32],[32]
    const float* __restrict__ W3, const float* __restrict__ b3,   // [32,32],[32]
    const float* __restrict__ W4, const float* __restrict__ b4,   // [32,16],[16]
    const float* __restrict__ Wv, const float* __restrict__ bv,   // [16,1],[1]
    const float* __restrict__ Wa, const float* __restrict__ ba,   // [16,4],[4]
    float* __restrict__ out,             // [B, 4]
    int B)
{
    const int b = blockIdx.x * blockDim.x + threadIdx.x;
    if (b >= B) return;

    const float fc0 = steer[b];
    const float fc1 = distance[b];
    const float fc2 = kmph[b];

    // layer 1: 3 -> 16, relu
    float h1[16];
    #pragma unroll
    for (int j = 0; j < 16; ++j) {
        float s = b1[j];
        s += fc0 * W1[0 * 16 + j];
        s += fc1 * W1[1 * 16 + j];
        s += fc2 * W1[2 * 16 + j];
        h1[j] = s > 0.0f ? s : 0.0f;
    }
    // layer 2: 16 -> 32, relu
    float h2[32];
    #pragma unroll
    for (int j = 0; j < 32; ++j) {
        float s = b2[j];
        #pragma unroll
        for (int i = 0; i < 16; ++i) s += h1[i] * W2[i * 32 + j];
        h2[j] = s > 0.0f ? s : 0.0f;
    }
    // layer 3: 32 -> 32, relu
    float h3[32];
    #pragma unroll
    for (int j = 0; j < 32; ++j) {
        float s = b3[j];
        #pragma unroll
        for (int i = 0; i < 32; ++i) s += h2[i] * W3[i * 32 + j];
        h3[j] = s > 0.0f ? s : 0.0f;
    }
    // layer 4: 32 -> 16 (no relu)
    float h4[16];
    #pragma unroll
    for (int j = 0; j < 16; ++j) {
        float s = b4[j];
        #pragma unroll
        for (int i = 0; i < 32; ++i) s += h3[i] * W4[i * 16 + j];
        h4[j] = s;
    }
    // value head 16 -> 1
    float value = bv[0];
    #pragma unroll
    for (int i = 0; i < 16; ++i) value += h4[i] * Wv[i];
    // advantage head 16 -> 4
    float a0 = ba[0], a1 = ba[1], a2 = ba[2], a3 = ba[3];
    #pragma unroll
    for (int i = 0; i < 16; ++i) {
        a0 += h4[i] * Wa[i * 4 + 0];
        a1 += h4[i] * Wa[i * 4 + 1];
        a2 += h4[i] * Wa[i * 4 + 2];
        a3 += h4[i] * Wa[i * 4 + 3];
    }
    float mean = (((a0 + a1) + a2) + a3) * 0.25f;

    float4 o;
    o.x = value + (a0 - mean);
    o.y = value + (a1 - mean);
    o.z = value + (a2 - mean);
    o.w = value + (a3 - mean);
    reinterpret_cast<float4*>(out)[b] = o;
}

extern "C" void kernel_launch(void* const* d_in, const int* in_sizes, int n_in,
                              void* d_out, int out_size, void* d_ws, size_t ws_size,
                              hipStream_t stream) {
    const float* rgb      = (const float*)d_in[0];
    const float* distance = (const float*)d_in[1];
    const float* kmph     = (const float*)d_in[2];
    const float* lane_W   = (const float*)d_in[3];
    const float* lane_b   = (const float*)d_in[4];
    const float* W1 = (const float*)d_in[5];
    const float* b1 = (const float*)d_in[6];
    const float* W2 = (const float*)d_in[7];
    const float* b2 = (const float*)d_in[8];
    const float* W3 = (const float*)d_in[9];
    const float* b3 = (const float*)d_in[10];
    const float* W4 = (const float*)d_in[11];
    const float* b4 = (const float*)d_in[12];
    const float* Wv = (const float*)d_in[13];
    const float* bv = (const float*)d_in[14];
    const float* Wa = (const float*)d_in[15];
    const float* ba = (const float*)d_in[16];

    const int B = in_sizes[1];          // distance has B elements

    float* wp    = (float*)d_ws;                 // 15000 floats = 60 KB
    float* steer = (float*)d_ws + 15104;         // [B] floats (offset 16B-aligned, past wp)

    eb_permute_w<<<(NPIX + 255) / 256, 256, 0, stream>>>(lane_W, wp);
    eb_reduce<<<B, 256, 0, stream>>>(rgb, wp, lane_b, steer);
    eb_mlp<<<(B + 255) / 256, 256, 0, stream>>>(steer, distance, kmph,
                                                W1, b1, W2, b2, W3, b3, W4, b4,
                                                Wv, bv, Wa, ba, (float*)d_out, B);
}

// Round 3
// 153.104 us; speedup vs baseline: 1.8838x; 1.2481x over previous
//
#include <hip/hip_runtime.h>

#define NPIX 15000
#define IMG_H 200
#define IMG_W 75
#define NVEC 3750   // NPIX / 4

typedef float f4 __attribute__((ext_vector_type(4)));

// Pre-kernel: wp[p] = lane_W[(p%200)*75 + p/200]  (the reshape/transpose permutation)
__global__ void eb_permute_w(const float* __restrict__ lane_W, float* __restrict__ wp) {
    int p = blockIdx.x * blockDim.x + threadIdx.x;
    if (p < NPIX) {
        int w = p / IMG_H;          // 0..74
        int h = p - w * IMG_H;      // 0..199
        wp[p] = lane_W[h * IMG_W + w];
    }
}

// Phase 1: steer[b] = sum_p (rgb[b,p] > 0 ? wp[p] : 0) + lane_b   (pure streaming)
__global__ __launch_bounds__(256, 8) void eb_reduce(
    const float* __restrict__ rgb,       // [B, 15000]
    const float* __restrict__ wp,        // [15000] permuted lane weights
    const float* __restrict__ lane_b,    // [1]
    float* __restrict__ steer)           // [B]
{
    const int b = blockIdx.x;
    const int t = threadIdx.x;

    const f4* __restrict__ row = reinterpret_cast<const f4*>(rgb + (size_t)b * NPIX);
    const f4* __restrict__ wv4 = reinterpret_cast<const f4*>(wp);

    float acc = 0.0f;
    int i = t;
    // unrolled x4: 8 independent 16B loads in flight per wave before first use
    #pragma unroll 1
    for (; i + 3 * 256 < NVEC; i += 4 * 256) {
        f4 v0 = __builtin_nontemporal_load(&row[i]);
        f4 v1 = __builtin_nontemporal_load(&row[i + 256]);
        f4 v2 = __builtin_nontemporal_load(&row[i + 512]);
        f4 v3 = __builtin_nontemporal_load(&row[i + 768]);
        f4 w0 = wv4[i];
        f4 w1 = wv4[i + 256];
        f4 w2 = wv4[i + 512];
        f4 w3 = wv4[i + 768];
        acc += (v0.x > 0.0f ? w0.x : 0.0f);
        acc += (v0.y > 0.0f ? w0.y : 0.0f);
        acc += (v0.z > 0.0f ? w0.z : 0.0f);
        acc += (v0.w > 0.0f ? w0.w : 0.0f);
        acc += (v1.x > 0.0f ? w1.x : 0.0f);
        acc += (v1.y > 0.0f ? w1.y : 0.0f);
        acc += (v1.z > 0.0f ? w1.z : 0.0f);
        acc += (v1.w > 0.0f ? w1.w : 0.0f);
        acc += (v2.x > 0.0f ? w2.x : 0.0f);
        acc += (v2.y > 0.0f ? w2.y : 0.0f);
        acc += (v2.z > 0.0f ? w2.z : 0.0f);
        acc += (v2.w > 0.0f ? w2.w : 0.0f);
        acc += (v3.x > 0.0f ? w3.x : 0.0f);
        acc += (v3.y > 0.0f ? w3.y : 0.0f);
        acc += (v3.z > 0.0f ? w3.z : 0.0f);
        acc += (v3.w > 0.0f ? w3.w : 0.0f);
    }
    // remainder (2-3 iterations per thread)
    for (; i < NVEC; i += 256) {
        f4 v = __builtin_nontemporal_load(&row[i]);
        f4 w = wv4[i];
        acc += (v.x > 0.0f ? w.x : 0.0f);
        acc += (v.y > 0.0f ? w.y : 0.0f);
        acc += (v.z > 0.0f ? w.z : 0.0f);
        acc += (v.w > 0.0f ? w.w : 0.0f);
    }

    #pragma unroll
    for (int off = 32; off > 0; off >>= 1)
        acc += __shfl_down(acc, off, 64);

    __shared__ float partial[4];
    const int wave = t >> 6;
    if ((t & 63) == 0) partial[wave] = acc;
    __syncthreads();

    if (t == 0)
        steer[b] = ((partial[0] + partial[1]) + (partial[2] + partial[3])) + lane_b[0];
}

// Phase 2: one thread per batch element runs the whole dueling MLP.
__global__ __launch_bounds__(256) void eb_mlp(
    const float* __restrict__ steer,     // [B]
    const float* __restrict__ distance,  // [B]
    const float* __restrict__ kmph,      // [B]
    const float* __restrict__ W1, const float* __restrict__ b1,   // [3,16],[16]
    const float* __restrict__ W2, const float* __restrict__ b2,   // [16,32],[32]
    const float* __restrict__ W3, const float* __restrict__ b3,   // [32,32],[32]
    const float* __restrict__ W4, const float* __restrict__ b4,   // [32,16],[16]
    const float* __restrict__ Wv, const float* __restrict__ bv,   // [16,1],[1]
    const float* __restrict__ Wa, const float* __restrict__ ba,   // [16,4],[4]
    float* __restrict__ out,             // [B, 4]
    int B)
{
    const int b = blockIdx.x * blockDim.x + threadIdx.x;
    if (b >= B) return;

    const float fc0 = steer[b];
    const float fc1 = distance[b];
    const float fc2 = kmph[b];

    // layer 1: 3 -> 16, relu
    float h1[16];
    #pragma unroll
    for (int j = 0; j < 16; ++j) {
        float s = b1[j];
        s += fc0 * W1[0 * 16 + j];
        s += fc1 * W1[1 * 16 + j];
        s += fc2 * W1[2 * 16 + j];
        h1[j] = s > 0.0f ? s : 0.0f;
    }
    // layer 2: 16 -> 32, relu
    float h2[32];
    #pragma unroll
    for (int j = 0; j < 32; ++j) {
        float s = b2[j];
        #pragma unroll
        for (int i = 0; i < 16; ++i) s += h1[i] * W2[i * 32 + j];
        h2[j] = s > 0.0f ? s : 0.0f;
    }
    // layer 3: 32 -> 32, relu
    float h3[32];
    #pragma unroll
    for (int j = 0; j < 32; ++j) {
        float s = b3[j];
        #pragma unroll
        for (int i = 0; i < 32; ++i) s += h2[i] * W3[i * 32 + j];
        h3[j] = s > 0.0f ? s : 0.0f;
    }
    // layer 4: 32 -> 16 (no relu)
    float h4[16];
    #pragma unroll
    for (int j = 0; j < 16; ++j) {
        float s = b4[j];
        #pragma unroll
        for (int i = 0; i < 32; ++i) s += h3[i] * W4[i * 16 + j];
        h4[j] = s;
    }
    // value head 16 -> 1
    float value = bv[0];
    #pragma unroll
    for (int i = 0; i < 16; ++i) value += h4[i] * Wv[i];
    // advantage head 16 -> 4
    float a0 = ba[0], a1 = ba[1], a2 = ba[2], a3 = ba[3];
    #pragma unroll
    for (int i = 0; i < 16; ++i) {
        a0 += h4[i] * Wa[i * 4 + 0];
        a1 += h4[i] * Wa[i * 4 + 1];
        a2 += h4[i] * Wa[i * 4 + 2];
        a3 += h4[i] * Wa[i * 4 + 3];
    }
    float mean = (((a0 + a1) + a2) + a3) * 0.25f;

    float4 o;
    o.x = value + (a0 - mean);
    o.y = value + (a1 - mean);
    o.z = value + (a2 - mean);
    o.w = value + (a3 - mean);
    reinterpret_cast<float4*>(out)[b] = o;
}

extern "C" void kernel_launch(void* const* d_in, const int* in_sizes, int n_in,
                              void* d_out, int out_size, void* d_ws, size_t ws_size,
                              hipStream_t stream) {
    const float* rgb      = (const float*)d_in[0];
    const float* distance = (const float*)d_in[1];
    const float* kmph     = (const float*)d_in[2];
    const float* lane_W   = (const float*)d_in[3];
    const float* lane_b   = (const float*)d_in[4];
    const float* W1 = (const float*)d_in[5];
    const float* b1 = (const float*)d_in[6];
    const float* W2 = (const float*)d_in[7];
    const float* b2 = (const float*)d_in[8];
    const float* W3 = (const float*)d_in[9];
    const float* b3 = (const float*)d_in[10];
    const float* W4 = (const float*)d_in[11];
    const float* b4 = (const float*)d_in[12];
    const float* Wv = (const float*)d_in[13];
    const float* bv = (const float*)d_in[14];
    const float* Wa = (const float*)d_in[15];
    const float* ba = (const float*)d_in[16];

    const int B = in_sizes[1];          // distance has B elements

    float* wp    = (float*)d_ws;                 // 15000 floats = 60 KB
    float* steer = (float*)d_ws + 15104;         // [B] floats (offset 16B-aligned, past wp)

    eb_permute_w<<<(NPIX + 255) / 256, 256, 0, stream>>>(lane_W, wp);
    eb_reduce<<<B, 256, 0, stream>>>(rgb, wp, lane_b, steer);
    eb_mlp<<<(B + 255) / 256, 256, 0, stream>>>(steer, distance, kmph,
                                                W1, b1, W2, b2, W3, b3, W4, b4,
                                                Wv, bv, Wa, ba, (float*)d_out, B);
}